// Round 1
// baseline (31.115 us; speedup 1.0000x reference)
//
#include <hip/hip_runtime.h>

#define NPTS 512
#define DIM  128
#define MARGIN 0.5f
#define CNT_EPS 1e-8f

// ---------------------------------------------------------------------------
// Kernel A: squared norms sq[i] = sum_d x[i][d]^2.  One wave per row.
// ---------------------------------------------------------------------------
__global__ void sq_norms_kernel(const float* __restrict__ x, float* __restrict__ sq) {
    const int i = blockIdx.x;
    const int t = threadIdx.x;           // 64 threads
    float s = 0.f;
    for (int d = t; d < DIM; d += 64) {
        float v = x[i * DIM + d];
        s += v * v;
    }
    for (int off = 32; off > 0; off >>= 1)
        s += __shfl_down(s, off, 64);
    if (t == 0) sq[i] = s;
}

// ---------------------------------------------------------------------------
// Kernel B: one block per anchor i.
//   - compute d[i][j] for all j (float4 dot products, row i cached in LDS)
//   - compact positives (d_ij + margin, j!=i, label match) and negatives
//     (d_ik, label mismatch) into LDS lists
//   - dense pos x neg pair loop -> per-block partial sum & positive count
// ---------------------------------------------------------------------------
__global__ __launch_bounds__(256)
void triplet_row_kernel(const float* __restrict__ x,
                        const int* __restrict__ labels,
                        const float* __restrict__ sq,
                        float* __restrict__ psum,
                        int* __restrict__ pcnt) {
    __shared__ float xi[DIM];
    __shared__ float pos[NPTS];
    __shared__ float neg[NPTS];
    __shared__ int   cnts[2];       // [0]=npos, [1]=nneg
    __shared__ float red_s[256];
    __shared__ int   red_c[256];

    const int i   = blockIdx.x;
    const int tid = threadIdx.x;

    if (tid < DIM) xi[tid] = x[i * DIM + tid];
    if (tid < 2)   cnts[tid] = 0;
    const int   li  = labels[i];
    const float sqi = sq[i];
    __syncthreads();

    const float4* xi4 = (const float4*)xi;
    for (int j = tid; j < NPTS; j += 256) {
        const float4* xj4 = (const float4*)(x + j * DIM);
        float dot = 0.f;
#pragma unroll
        for (int q = 0; q < DIM / 4; ++q) {
            float4 a = xi4[q];
            float4 b = xj4[q];
            dot += a.x * b.x + a.y * b.y + a.z * b.z + a.w * b.w;
        }
        float dsq = sqi + sq[j] - 2.f * dot;
        dsq = dsq > 0.f ? dsq : 0.f;
        // reference's zero-mask path only changes exact-zero entries (the
        // diagonal), which the validity mask excludes -> plain sqrt is exact.
        float dist = (dsq == 0.f) ? 0.f : sqrtf(dsq);

        int lj = labels[j];
        if (lj == li) {
            if (j != i) {
                int p = atomicAdd(&cnts[0], 1);
                pos[p] = dist + MARGIN;
            }
        } else {
            int q = atomicAdd(&cnts[1], 1);
            neg[q] = dist;
        }
    }
    __syncthreads();

    const int npos = cnts[0];
    const int nneg = cnts[1];

    float lsum = 0.f;
    int   lcnt = 0;
    for (int p = 0; p < npos; ++p) {
        const float a = pos[p];
        for (int k = tid; k < nneg; k += 256) {
            float v = a - neg[k];            // d_ij - d_ik + margin
            if (v > 0.f) {
                lsum += v;
                lcnt += (v > CNT_EPS) ? 1 : 0;
            }
        }
    }

    red_s[tid] = lsum;
    red_c[tid] = lcnt;
    __syncthreads();
    for (int s = 128; s > 0; s >>= 1) {
        if (tid < s) {
            red_s[tid] += red_s[tid + s];
            red_c[tid] += red_c[tid + s];
        }
        __syncthreads();
    }
    if (tid == 0) {
        psum[i] = red_s[0];
        pcnt[i] = red_c[0];
    }
}

// ---------------------------------------------------------------------------
// Kernel C: reduce 512 per-block partials, out = sum / count.
// ---------------------------------------------------------------------------
__global__ void finalize_kernel(const float* __restrict__ psum,
                                const int* __restrict__ pcnt,
                                float* __restrict__ out) {
    __shared__ float rs[256];
    __shared__ int   rc[256];
    const int tid = threadIdx.x;
    float s = psum[tid] + psum[tid + 256];
    int   c = pcnt[tid] + pcnt[tid + 256];
    rs[tid] = s;
    rc[tid] = c;
    __syncthreads();
    for (int st = 128; st > 0; st >>= 1) {
        if (tid < st) {
            rs[tid] += rs[tid + st];
            rc[tid] += rc[tid + st];
        }
        __syncthreads();
    }
    if (tid == 0) out[0] = rs[0] / (float)rc[0];
}

extern "C" void kernel_launch(void* const* d_in, const int* in_sizes, int n_in,
                              void* d_out, int out_size, void* d_ws, size_t ws_size,
                              hipStream_t stream) {
    const float* x      = (const float*)d_in[0];   // [512,128] fp32
    const int*   labels = (const int*)d_in[1];     // [512] int32
    float*       out    = (float*)d_out;           // scalar fp32

    float* sq   = (float*)d_ws;          // 512 floats
    float* psum = sq + NPTS;             // 512 floats
    int*   pcnt = (int*)(psum + NPTS);   // 512 ints

    sq_norms_kernel<<<NPTS, 64, 0, stream>>>(x, sq);
    triplet_row_kernel<<<NPTS, 256, 0, stream>>>(x, labels, sq, psum, pcnt);
    finalize_kernel<<<1, 256, 0, stream>>>(psum, pcnt, out);
}